// Round 1
// baseline (387.095 us; speedup 1.0000x reference)
//
#include <hip/hip_runtime.h>
#include <stdint.h>
#include <math.h>

#define N0 8192
#define HH 128
#define KN 5
#define SMALLD 31   // columns with (non-self in-deg) <= SMALLD use exact sequential gather
#define EL 16       // rank kernel: elements per block
#define CHK 16      // rank kernel: chunk-threads per element
#define NBLK 512    // gemm blocks per level (n/RB == 512 at every level)
#define PBLK 128    // poolmap blocks per level (m/PR == 128 at every level)

__device__ inline void atomAddD(double* a, double v){
  __hip_atomic_fetch_add(a, v, __ATOMIC_RELAXED, __HIP_MEMORY_SCOPE_AGENT);
}

// ---- fused graph-structure kernel (single block, 1024 threads) ----
// (optional MODE0 knn init) + degree hist (LDS, wave-leader aggregated for hub
// columns) + dinv + small in-edge lists (filled, self-appended, sorted asc) +
// zero TsPart.
__global__ __launch_bounds__(1024) void graph_kernel(int* nbr, int n, int init,
    int* degi, float* dinvf, int* cnt, int* slots, double* TsPart){
  extern __shared__ int lds[];
  int* hist = lds;        // n ints
  int* cntL = lds + n;    // n ints
  const int t = threadIdx.x;
  const int lane = t & 63;
  if (init){
    for (int i=t;i<n;i+=1024){
      nbr[i*KN+0] = -1;                       // self (dedup vs implicit self-loop)
      int q=1, j=0;
      while (q<KN){ if (j!=i) nbr[i*KN+(q++)]=j; j++; }
    }
  }
  for (int i=t;i<n;i+=1024){ hist[i]=0; cntL[i]=0; }
  if (t<256) TsPart[t]=0.0;
  __syncthreads();
  // degree count; leader aggregation: hub targets are wave-uniform -> 1 atomic/wave
  for (int r=t;r<n;r+=1024){
    #pragma unroll
    for (int e=0;e<KN;e++){
      int c = nbr[r*KN+e];
      if (c>=0){
        int v = __builtin_amdgcn_readfirstlane(c);
        unsigned long long eq = __ballot(c==v);
        if (c==v){
          if ((eq & ((1ULL<<lane)-1ULL))==0ULL) atomicAdd(&hist[v], (int)__popcll(eq));
        } else {
          atomicAdd(&hist[c], 1);
        }
      }
    }
  }
  __syncthreads();
  for (int c2=t;c2<n;c2+=1024){
    degi[c2]=hist[c2];
    dinvf[c2]=1.0f/sqrtf((float)(hist[c2]+1));  // f32 CR sqrt+div, matches np
  }
  __syncthreads();
  // small-column in-edge fill (hubs skipped via hist guard)
  for (int r=t;r<n;r+=1024){
    #pragma unroll
    for (int e=0;e<KN;e++){
      int c = nbr[r*KN+e];
      if (c>=0 && hist[c]<=SMALLD){
        int p = atomicAdd(&cntL[c],1);
        if (p<32) slots[c*32+p]=r;
      }
    }
  }
  __syncthreads();
  // append self, insertion-sort ascending, publish cnt
  for (int c2=t;c2<n;c2+=1024){
    if (hist[c2]<=SMALLD){
      int m = cntL[c2];
      slots[c2*32+m]=c2; m++;
      for (int a=1;a<m;a++){
        int v2=slots[c2*32+a]; int b=a-1;
        while (b>=0 && slots[c2*32+b]>v2){ slots[c2*32+b+1]=slots[c2*32+b]; b--; }
        slots[c2*32+b+1]=v2;
      }
      cnt[c2]=m;
    }
  }
}

// G[r][j] = sequential f32 FMA dot (k = 0..127 ascending), bit-identical to the
// old 1-row-per-block gemm32.  W column j lives in 128 VGPRs (loaded once per
// block, coalesced across lanes); x-row elements arrive as wave-uniform scalar
// loads (SGPR operand on the FMA).  Two interleaved rows hide FMA latency.
// Fused tpar: per-block f64 T-partial (rows ascending), full overwrite of
// TsBlk[b][j] -> no init, no atomics, deterministic reduction in aggproj.
__global__ __launch_bounds__(128) void gemmT_kernel(const float* __restrict__ X,
    const float* __restrict__ W, const float* __restrict__ dinvf,
    float* __restrict__ G, double* __restrict__ TsBlk, int RB){
  const int j = threadIdx.x;
  const int r0 = blockIdx.x * RB;
  float w[HH];
  #pragma unroll
  for (int k=0;k<HH;k++) w[k] = W[k*HH+j];   // coalesced across lanes, once/block
  double tacc = 0.0;
  for (int p=0;p<RB;p+=2){
    const float* xa = X + (size_t)(r0+p)*HH;   // wave-uniform base -> s_load
    const float* xb = xa + HH;
    float accA = 0.0f, accB = 0.0f;
    #pragma unroll
    for (int k=0;k<HH;k++){
      accA = fmaf(xa[k], w[k], accA);
      accB = fmaf(xb[k], w[k], accB);
    }
    G[(size_t)(r0+p)*HH+j]   = accA;
    G[(size_t)(r0+p+1)*HH+j] = accB;
    tacc += (double)dinvf[r0+p]  *(double)accA;   // row-ascending order
    tacc += (double)dinvf[r0+p+1]*(double)accB;
  }
  TsBlk[(size_t)blockIdx.x*HH+j] = tacc;
}

// fused: feature aggregation + relu + score projection + Ts partial
// hub path: T[j] = sum_b TsBlk[b][j] in fixed b-ascending order (deterministic).
__global__ __launch_bounds__(128) void aggproj_kernel(const float* __restrict__ G,
    const float* __restrict__ dinvf, const int* __restrict__ degi,
    const int* __restrict__ cnt, const int* __restrict__ slots,
    const double* __restrict__ TsBlk, const float* __restrict__ Wp,
    float* __restrict__ hout, float* __restrict__ y, double* TsPart, int n){
  __shared__ float hrow[HH];
  int c = blockIdx.x, j = threadIdx.x;
  float v;
  if (degi[c] <= SMALLD){
    float acc = 0.0f, dc = dinvf[c];
    int m = cnt[c];
    for (int a=0;a<m;a++){
      int r = slots[c*32+a];
      acc = fmaf(dinvf[r]*dc, G[(size_t)r*HH+j], acc);
    }
    v = acc;
  } else {
    double T = 0.0;
    for (int b=0;b<NBLK;b++) T += TsBlk[(size_t)b*HH+j];   // fixed order
    v = (float)((double)dinvf[c]*T);
  }
  v = v<0.0f ? 0.0f : v;                    // relu
  hout[(size_t)c*HH+j] = v;
  hrow[j] = v;
  __syncthreads();
  if (j==0){
    float acc = 0.0f;
    for (int k=0;k<HH;k++) acc = fmaf(hrow[k], Wp[k], acc);
    y[c] = acc;
    atomAddD(&TsPart[c & 255], (double)dinvf[c]*(double)acc);
  }
}

// score aggregation + key build; Ts recovered from partials in fixed order
__global__ __launch_bounds__(256) void sagg32_kernel(const float* __restrict__ y,
    const float* __restrict__ dinvf, const int* __restrict__ degi,
    const int* __restrict__ cnt, const int* __restrict__ slots,
    const double* __restrict__ TsPart, float* score, unsigned* key, int n){
  __shared__ double tp[256];
  tp[threadIdx.x] = TsPart[threadIdx.x];
  __syncthreads();
  for (int o=128;o>0;o>>=1){ if (threadIdx.x<o) tp[threadIdx.x]+=tp[threadIdx.x+o]; __syncthreads(); }
  double Ts = tp[0];                        // identical in every block (fixed order)
  int c = blockIdx.x*256+threadIdx.x; if (c>=n) return;
  float sc;
  if (degi[c] <= SMALLD){
    float acc = 0.0f, dc = dinvf[c];
    int m = cnt[c];
    for (int a=0;a<m;a++){ int r = slots[c*32+a]; acc = fmaf(dinvf[r]*dc, y[r], acc); }
    sc = acc;
  } else {
    sc = (float)((double)dinvf[c]*Ts);
  }
  score[c] = sc;
  unsigned s = __float_as_uint(sc);
  unsigned u = (s>>31) ? ~s : (s | 0x80000000u);   // order-preserving map
  key[c] = ~u;                                      // ascending key == descending score
}

// rank-by-counting stable top-k (bit-identical to stable desc sort + asc ties)
__global__ __launch_bounds__(256) void rank_kernel(
    const unsigned* __restrict__ key, const float* __restrict__ score, int n,
    int* out_idx, float* gate, int* pos,
    const int* __restrict__ perm_prev, int* perm_next){
  __shared__ unsigned psum[EL][CHK+1];
  const int t = threadIdx.x;
  const int e = t & (EL-1), c = t >> 4;
  const int i = blockIdx.x*EL + e;
  const unsigned ke = key[i];
  const int L = n / CHK;
  const int j0 = c*L;
  unsigned cnt = 0;
  for (int j=j0; j<j0+L; j++){
    unsigned kj = key[j];
    cnt += (kj < ke || (kj == ke && j < i)) ? 1u : 0u;
  }
  psum[e][c] = cnt;
  __syncthreads();
  if (c == 0){
    unsigned r = 0;
    #pragma unroll
    for (int q=0;q<CHK;q++) r += psum[e][q];
    int m = n>>1;
    if ((int)r < m){
      out_idx[r] = i;
      gate[r] = (float)tanh((double)score[i]);   // correctly-rounded f32 tanh
      pos[i] = (int)r;
      perm_next[r] = perm_prev ? perm_prev[i] : i;
    } else {
      pos[i] = -1;
    }
  }
}

// fused pool (gate multiply) + neighbor remap + readout partials.
// Each block owns PR consecutive output rows; thread j keeps a running
// f32 col-max and f64 col-sum (row-ascending) over its rows, then writes one
// partial per column (full overwrite, no init, no atomics).  Epilogue reduces
// the 128 partials in fixed block-ascending order.
__global__ __launch_bounds__(128) void poolmap_kernel(const float* __restrict__ h,
    const int* __restrict__ idx, const float* __restrict__ gate,
    const int* __restrict__ nbr_prev, const int* __restrict__ pos,
    float* hp, int* nbr_next, float* __restrict__ rmaxB, double* __restrict__ rsumB,
    int PR){
  const int j = threadIdx.x;
  const int i0 = blockIdx.x*PR;
  float mx = -INFINITY;
  double sm = 0.0;
  for (int p=0;p<PR;p++){
    int i = i0+p;
    int g = idx[i];
    float v = h[(size_t)g*HH+j]*gate[i];
    hp[(size_t)i*HH+j] = v;
    mx = fmaxf(mx, v);
    sm += (double)v;
    if (j < KN){
      int o = nbr_prev[g*KN+j];
      nbr_next[i*KN+j] = (o>=0) ? pos[o] : -1;
    }
  }
  rmaxB[(size_t)blockIdx.x*HH+j] = mx;
  rsumB[(size_t)blockIdx.x*HH+j] = sm;
}

// fused epilogue: a3 rows (full overwrite, no memset) | xs rows | perm | mlp
// (readout partial reduction folded into the mlp block, fixed order)
__global__ __launch_bounds__(256) void epilogue_kernel(const float* __restrict__ kp,
    const int* __restrict__ perm3, const int* __restrict__ nbr3,
    const float* __restrict__ rmax1, const float* __restrict__ rmax2, const float* __restrict__ rmax3,
    const double* __restrict__ rsum1, const double* __restrict__ rsum2, const double* __restrict__ rsum3,
    const float* __restrict__ L1w, const float* __restrict__ L2w, const float* __restrict__ L3w,
    float* out_logp, float* out_xs, float* out_perm, float* out_a3){
  __shared__ double z[256], z1[128], z2[64], z3[40];
  int b = blockIdx.x, t = threadIdx.x;
  if (b < 1024){
    int s0=nbr3[b*KN+0], s1=nbr3[b*KN+1], s2=nbr3[b*KN+2], s3=nbr3[b*KN+3], s4=nbr3[b*KN+4];
    #pragma unroll
    for (int q=0;q<4;q++){
      int col = t + 256*q;
      float v = (col==b||col==s0||col==s1||col==s2||col==s3||col==s4) ? 1.0f : 0.0f;
      out_a3[(size_t)b*1024+col] = v;
    }
  } else if (b < 2048){
    int i = b-1024;
    if (t < HH) out_xs[(size_t)i*HH+t] = kp[(size_t)perm3[i]*HH+t];
  } else if (b == 2048){
    for (int q=t;q<1024;q+=256) out_perm[q] = (float)perm3[q];
  } else {
    if (t < 128){
      float m1=-INFINITY, m2=-INFINITY, m3=-INFINITY;
      for (int q=0;q<PBLK;q++){
        m1 = fmaxf(m1, rmax1[(size_t)q*HH+t]);
        m2 = fmaxf(m2, rmax2[(size_t)q*HH+t]);
        m3 = fmaxf(m3, rmax3[(size_t)q*HH+t]);
      }
      z[t] = (double)m1 + (double)m2 + (double)m3;
    } else {
      int c = t-128;
      double s1=0.0, s2=0.0, s3=0.0;
      for (int q=0;q<PBLK;q++){
        s1 += rsum1[(size_t)q*HH+c];
        s2 += rsum2[(size_t)q*HH+c];
        s3 += rsum3[(size_t)q*HH+c];
      }
      z[t] = s1/4096.0 + s2/2048.0 + s3/1024.0;
    }
    __syncthreads();
    if (t<128){ double a=0; for(int k=0;k<256;k++) a += z[k]*(double)L1w[k*128+t]; z1[t]=a>0?a:0; }
    __syncthreads();
    if (t<64){ double a=0; for(int k=0;k<128;k++) a += z1[k]*(double)L2w[k*64+t]; z2[t]=a>0?a:0; }
    __syncthreads();
    if (t<40){ double a=0; for(int k=0;k<64;k++) a += z2[k]*(double)L3w[k*40+t]; z3[t]=a; }
    __syncthreads();
    if (t==0){
      double m=-INFINITY; for(int j=0;j<40;j++) m=fmax(m,z3[j]);
      double s=0; for(int j=0;j<40;j++) s+=exp(z3[j]-m);
      double l=log(s);
      for(int j=0;j<40;j++) out_logp[j] = (float)(z3[j]-m-l);
    }
  }
}

__global__ void enc_kernel(float* out, float v){
  if (threadIdx.x < 40) out[threadIdx.x] = v;
}

extern "C" void kernel_launch(void* const* d_in, const int* in_sizes, int n_in,
                              void* d_out, int out_size, void* d_ws, size_t ws_size,
                              hipStream_t stream){
  const float* kp  = (const float*)d_in[0];
  const float* W1  = (const float*)d_in[2];
  const float* W2  = (const float*)d_in[4];
  const float* W3  = (const float*)d_in[6];
  const float* Wp1 = (const float*)d_in[8];
  const float* Wp2 = (const float*)d_in[10];
  const float* Wp3 = (const float*)d_in[12];
  const float* L1w = (const float*)d_in[14];
  const float* L2w = (const float*)d_in[16];
  const float* L3w = (const float*)d_in[18];

  float* out = (float*)d_out;
  if (out_size != 40 + 128*1024 + 1024 + 1024*1024){
    enc_kernel<<<1,64,0,stream>>>(out, (float)out_size);
    return;
  }

  char* p = (char*)d_ws;
  auto alloc = [&](size_t bytes)->char*{ char* q = p; p += (bytes + 255) & ~(size_t)255; return q; };
  float* G     = (float*)alloc((size_t)N0*HH*4);
  float* h     = (float*)alloc((size_t)N0*HH*4);
  float* hpA   = (float*)alloc((size_t)4096*HH*4);
  float* hpB   = (float*)alloc((size_t)2048*HH*4);
  int* degi    = (int*)alloc(N0*4);
  float* dinvf = (float*)alloc(N0*4);
  int* cnt     = (int*)alloc(N0*4);
  int* slots   = (int*)alloc((size_t)N0*32*4);
  int* nbr0    = (int*)alloc(N0*KN*4);
  int* nbr1    = (int*)alloc(4096*KN*4);
  int* nbr2    = (int*)alloc(2048*KN*4);
  int* nbr3    = (int*)alloc(1024*KN*4);
  int* idx1    = (int*)alloc(4096*4);
  int* idx2    = (int*)alloc(2048*4);
  int* idx3    = (int*)alloc(1024*4);
  int* perm1   = (int*)alloc(4096*4);
  int* perm2   = (int*)alloc(2048*4);
  int* perm3   = (int*)alloc(1024*4);
  int* pos     = (int*)alloc(N0*4);
  float* ybuf  = (float*)alloc(N0*4);
  float* score = (float*)alloc(N0*4);
  unsigned* skey = (unsigned*)alloc(N0*4);
  float* gate  = (float*)alloc(4096*4);
  double* TsBlk = (double*)alloc((size_t)NBLK*HH*8);
  double* TsPart = (double*)alloc(256*8);
  float* rmax1 = (float*)alloc((size_t)PBLK*HH*4);
  float* rmax2 = (float*)alloc((size_t)PBLK*HH*4);
  float* rmax3 = (float*)alloc((size_t)PBLK*HH*4);
  double* rsum1 = (double*)alloc((size_t)PBLK*HH*8);
  double* rsum2 = (double*)alloc((size_t)PBLK*HH*8);
  double* rsum3 = (double*)alloc((size_t)PBLK*HH*8);

  float* out_logp = out;
  float* out_xs   = out + 40;
  float* out_perm = out + 40 + 128*1024;
  float* out_a3   = out_perm + 1024;

  auto run_level = [&](int n, int init, const float* X, const float* W, const float* Wp,
                       int* nbr, int* nbrN, int* idx, int* permPrev, int* permNext,
                       float* hp, float* rmaxB, double* rsumB){
    int m = n>>1;
    graph_kernel<<<1,1024,(size_t)n*8,stream>>>(nbr, n, init, degi, dinvf, cnt, slots, TsPart);
    gemmT_kernel<<<NBLK,HH,0,stream>>>(X, W, dinvf, G, TsBlk, n/NBLK);
    aggproj_kernel<<<n,HH,0,stream>>>(G, dinvf, degi, cnt, slots, TsBlk, Wp, h, ybuf, TsPart, n);
    sagg32_kernel<<<(n+255)/256,256,0,stream>>>(ybuf, dinvf, degi, cnt, slots, TsPart, score, skey, n);
    rank_kernel<<<n/EL,256,0,stream>>>(skey, score, n, idx, gate, pos, permPrev, permNext);
    poolmap_kernel<<<PBLK,HH,0,stream>>>(h, idx, gate, nbr, pos, hp, nbrN, rmaxB, rsumB, m/PBLK);
  };

  run_level(8192, 1, kp,  W1, Wp1, nbr0, nbr1, idx1, nullptr, perm1, hpA, rmax1, rsum1);
  run_level(4096, 0, hpA, W2, Wp2, nbr1, nbr2, idx2, perm1,   perm2, hpB, rmax2, rsum2);
  run_level(2048, 0, hpB, W3, Wp3, nbr2, nbr3, idx3, perm2,   perm3, hpA, rmax3, rsum3);

  epilogue_kernel<<<2050,256,0,stream>>>(kp, perm3, nbr3,
                                         rmax1, rmax2, rmax3, rsum1, rsum2, rsum3,
                                         L1w, L2w, L3w,
                                         out_logp, out_xs, out_perm, out_a3);
}

// Round 2
// 386.930 us; speedup vs baseline: 1.0004x; 1.0004x over previous
//
#include <hip/hip_runtime.h>
#include <stdint.h>
#include <math.h>

#define N0 8192
#define HH 128
#define KN 5
#define SMALLD 31   // columns with (non-self in-deg) <= SMALLD use exact sequential gather
#define EL 16       // rank kernel: elements per block
#define CHK 16      // rank kernel: chunk-threads per element
#define NBLK 512    // gemm blocks per level (n/RB == 512 at every level)
#define PBLK 128    // poolmap blocks per level (m/PR == 128 at every level)

__device__ inline void atomAddD(double* a, double v){
  __hip_atomic_fetch_add(a, v, __ATOMIC_RELAXED, __HIP_MEMORY_SCOPE_AGENT);
}

// ---- fused graph-structure kernel (single block, 1024 threads) ----
// (optional MODE0 knn init) + degree hist (LDS, wave-leader aggregated for hub
// columns) + dinv + small in-edge lists (filled, self-appended, sorted asc) +
// zero TsPart.
__global__ __launch_bounds__(1024) void graph_kernel(int* nbr, int n, int init,
    int* degi, float* dinvf, int* cnt, int* slots, double* TsPart){
  extern __shared__ int lds[];
  int* hist = lds;        // n ints
  int* cntL = lds + n;    // n ints
  const int t = threadIdx.x;
  const int lane = t & 63;
  if (init){
    for (int i=t;i<n;i+=1024){
      nbr[i*KN+0] = -1;                       // self (dedup vs implicit self-loop)
      int q=1, j=0;
      while (q<KN){ if (j!=i) nbr[i*KN+(q++)]=j; j++; }
    }
  }
  for (int i=t;i<n;i+=1024){ hist[i]=0; cntL[i]=0; }
  if (t<256) TsPart[t]=0.0;
  __syncthreads();
  // degree count; leader aggregation: hub targets are wave-uniform -> 1 atomic/wave
  for (int r=t;r<n;r+=1024){
    #pragma unroll
    for (int e=0;e<KN;e++){
      int c = nbr[r*KN+e];
      if (c>=0){
        int v = __builtin_amdgcn_readfirstlane(c);
        unsigned long long eq = __ballot(c==v);
        if (c==v){
          if ((eq & ((1ULL<<lane)-1ULL))==0ULL) atomicAdd(&hist[v], (int)__popcll(eq));
        } else {
          atomicAdd(&hist[c], 1);
        }
      }
    }
  }
  __syncthreads();
  for (int c2=t;c2<n;c2+=1024){
    degi[c2]=hist[c2];
    dinvf[c2]=1.0f/sqrtf((float)(hist[c2]+1));  // f32 CR sqrt+div, matches np
  }
  __syncthreads();
  // small-column in-edge fill (hubs skipped via hist guard)
  for (int r=t;r<n;r+=1024){
    #pragma unroll
    for (int e=0;e<KN;e++){
      int c = nbr[r*KN+e];
      if (c>=0 && hist[c]<=SMALLD){
        int p = atomicAdd(&cntL[c],1);
        if (p<32) slots[c*32+p]=r;
      }
    }
  }
  __syncthreads();
  // append self, insertion-sort ascending, publish cnt
  for (int c2=t;c2<n;c2+=1024){
    if (hist[c2]<=SMALLD){
      int m = cntL[c2];
      slots[c2*32+m]=c2; m++;
      for (int a=1;a<m;a++){
        int v2=slots[c2*32+a]; int b=a-1;
        while (b>=0 && slots[c2*32+b]>v2){ slots[c2*32+b+1]=slots[c2*32+b]; b--; }
        slots[c2*32+b+1]=v2;
      }
      cnt[c2]=m;
    }
  }
}

// G[r][j] = sequential f32 FMA dot (k = 0..127 ascending), bit-identical to the
// old 1-row-per-block gemm32.  W column j lives in 128 VGPRs (loaded once per
// block, coalesced across lanes); x-row elements arrive as wave-uniform scalar
// loads (SGPR operand on the FMA).  Two interleaved rows hide FMA latency.
// Fused tpar: per-block f64 T-partial (rows ascending), full overwrite of
// TsBlk[b][j] -> no init, no atomics, deterministic reduction in aggproj.
__global__ __launch_bounds__(128) void gemmT_kernel(const float* __restrict__ X,
    const float* __restrict__ W, const float* __restrict__ dinvf,
    float* __restrict__ G, double* __restrict__ TsBlk, int RB){
  const int j = threadIdx.x;
  const int r0 = blockIdx.x * RB;
  float w[HH];
  #pragma unroll
  for (int k=0;k<HH;k++) w[k] = W[k*HH+j];   // coalesced across lanes, once/block
  double tacc = 0.0;
  for (int p=0;p<RB;p+=2){
    const float* xa = X + (size_t)(r0+p)*HH;   // wave-uniform base -> s_load
    const float* xb = xa + HH;
    float accA = 0.0f, accB = 0.0f;
    #pragma unroll
    for (int k=0;k<HH;k++){
      accA = fmaf(xa[k], w[k], accA);
      accB = fmaf(xb[k], w[k], accB);
    }
    G[(size_t)(r0+p)*HH+j]   = accA;
    G[(size_t)(r0+p+1)*HH+j] = accB;
    tacc += (double)dinvf[r0+p]  *(double)accA;   // row-ascending order
    tacc += (double)dinvf[r0+p+1]*(double)accB;
  }
  TsBlk[(size_t)blockIdx.x*HH+j] = tacc;
}

// fused: feature aggregation + relu + score projection + Ts partial
// hub path: T[j] = sum_b TsBlk[b][j] in fixed b-ascending order (deterministic).
__global__ __launch_bounds__(128) void aggproj_kernel(const float* __restrict__ G,
    const float* __restrict__ dinvf, const int* __restrict__ degi,
    const int* __restrict__ cnt, const int* __restrict__ slots,
    const double* __restrict__ TsBlk, const float* __restrict__ Wp,
    float* __restrict__ hout, float* __restrict__ y, double* TsPart, int n){
  __shared__ float hrow[HH];
  int c = blockIdx.x, j = threadIdx.x;
  float v;
  if (degi[c] <= SMALLD){
    float acc = 0.0f, dc = dinvf[c];
    int m = cnt[c];
    for (int a=0;a<m;a++){
      int r = slots[c*32+a];
      acc = fmaf(dinvf[r]*dc, G[(size_t)r*HH+j], acc);
    }
    v = acc;
  } else {
    double T = 0.0;
    for (int b=0;b<NBLK;b++) T += TsBlk[(size_t)b*HH+j];   // fixed order
    v = (float)((double)dinvf[c]*T);
  }
  v = v<0.0f ? 0.0f : v;                    // relu
  hout[(size_t)c*HH+j] = v;
  hrow[j] = v;
  __syncthreads();
  if (j==0){
    float acc = 0.0f;
    for (int k=0;k<HH;k++) acc = fmaf(hrow[k], Wp[k], acc);
    y[c] = acc;
    atomAddD(&TsPart[c & 255], (double)dinvf[c]*(double)acc);
  }
}

// score aggregation + key build; Ts recovered from partials in fixed order
__global__ __launch_bounds__(256) void sagg32_kernel(const float* __restrict__ y,
    const float* __restrict__ dinvf, const int* __restrict__ degi,
    const int* __restrict__ cnt, const int* __restrict__ slots,
    const double* __restrict__ TsPart, float* score, unsigned* key, int n){
  __shared__ double tp[256];
  tp[threadIdx.x] = TsPart[threadIdx.x];
  __syncthreads();
  for (int o=128;o>0;o>>=1){ if (threadIdx.x<o) tp[threadIdx.x]+=tp[threadIdx.x+o]; __syncthreads(); }
  double Ts = tp[0];                        // identical in every block (fixed order)
  int c = blockIdx.x*256+threadIdx.x; if (c>=n) return;
  float sc;
  if (degi[c] <= SMALLD){
    float acc = 0.0f, dc = dinvf[c];
    int m = cnt[c];
    for (int a=0;a<m;a++){ int r = slots[c*32+a]; acc = fmaf(dinvf[r]*dc, y[r], acc); }
    sc = acc;
  } else {
    sc = (float)((double)dinvf[c]*Ts);
  }
  score[c] = sc;
  unsigned s = __float_as_uint(sc);
  unsigned u = (s>>31) ? ~s : (s | 0x80000000u);   // order-preserving map
  key[c] = ~u;                                      // ascending key == descending score
}

// rank-by-counting stable top-k (bit-identical to stable desc sort + asc ties)
__global__ __launch_bounds__(256) void rank_kernel(
    const unsigned* __restrict__ key, const float* __restrict__ score, int n,
    int* out_idx, float* gate, int* pos,
    const int* __restrict__ perm_prev, int* perm_next){
  __shared__ unsigned psum[EL][CHK+1];
  const int t = threadIdx.x;
  const int e = t & (EL-1), c = t >> 4;
  const int i = blockIdx.x*EL + e;
  const unsigned ke = key[i];
  const int L = n / CHK;
  const int j0 = c*L;
  unsigned cnt = 0;
  for (int j=j0; j<j0+L; j++){
    unsigned kj = key[j];
    cnt += (kj < ke || (kj == ke && j < i)) ? 1u : 0u;
  }
  psum[e][c] = cnt;
  __syncthreads();
  if (c == 0){
    unsigned r = 0;
    #pragma unroll
    for (int q=0;q<CHK;q++) r += psum[e][q];
    int m = n>>1;
    if ((int)r < m){
      out_idx[r] = i;
      gate[r] = (float)tanh((double)score[i]);   // correctly-rounded f32 tanh
      pos[i] = (int)r;
      perm_next[r] = perm_prev ? perm_prev[i] : i;
    } else {
      pos[i] = -1;
    }
  }
}

// fused pool (gate multiply) + neighbor remap + readout partials.
// Each block owns PR consecutive output rows; thread j keeps a running
// f32 col-max and f64 col-sum (row-ascending) over its rows, then writes one
// partial per column (full overwrite, no init, no atomics).  Epilogue reduces
// the 128 partials in fixed block-ascending order.
__global__ __launch_bounds__(128) void poolmap_kernel(const float* __restrict__ h,
    const int* __restrict__ idx, const float* __restrict__ gate,
    const int* __restrict__ nbr_prev, const int* __restrict__ pos,
    float* hp, int* nbr_next, float* __restrict__ rmaxB, double* __restrict__ rsumB,
    int PR){
  const int j = threadIdx.x;
  const int i0 = blockIdx.x*PR;
  float mx = -INFINITY;
  double sm = 0.0;
  for (int p=0;p<PR;p++){
    int i = i0+p;
    int g = idx[i];
    float v = h[(size_t)g*HH+j]*gate[i];
    hp[(size_t)i*HH+j] = v;
    mx = fmaxf(mx, v);
    sm += (double)v;
    if (j < KN){
      int o = nbr_prev[g*KN+j];
      nbr_next[i*KN+j] = (o>=0) ? pos[o] : -1;
    }
  }
  rmaxB[(size_t)blockIdx.x*HH+j] = mx;
  rsumB[(size_t)blockIdx.x*HH+j] = sm;
}

// fused epilogue: a3 rows (full overwrite, no memset) | xs rows | perm | mlp
// MLP block: readout partial reduction done by all 256 threads, coalesced,
// 16-wide load batches (one waitcnt per 16 loads) -> MLP -> parallel softmax.
// Sum/exp accumulation order is unchanged (q-ascending / j-ascending) ->
// bit-identical to the sequential version.
__global__ __launch_bounds__(256) void epilogue_kernel(const float* __restrict__ kp,
    const int* __restrict__ perm3, const int* __restrict__ nbr3,
    const float* __restrict__ rmax1, const float* __restrict__ rmax2, const float* __restrict__ rmax3,
    const double* __restrict__ rsum1, const double* __restrict__ rsum2, const double* __restrict__ rsum3,
    const float* __restrict__ L1w, const float* __restrict__ L2w, const float* __restrict__ L3w,
    float* out_logp, float* out_xs, float* out_perm, float* out_a3){
  int b = blockIdx.x, t = threadIdx.x;
  if (b < 1024){
    int s0=nbr3[b*KN+0], s1=nbr3[b*KN+1], s2=nbr3[b*KN+2], s3=nbr3[b*KN+3], s4=nbr3[b*KN+4];
    #pragma unroll
    for (int q=0;q<4;q++){
      int col = t + 256*q;
      float v = (col==b||col==s0||col==s1||col==s2||col==s3||col==s4) ? 1.0f : 0.0f;
      out_a3[(size_t)b*1024+col] = v;
    }
  } else if (b < 2048){
    int i = b-1024;
    if (t < HH) out_xs[(size_t)i*HH+t] = kp[(size_t)perm3[i]*HH+t];
  } else if (b == 2048){
    for (int q=t;q<1024;q+=256) out_perm[q] = (float)perm3[q];
  } else {
    __shared__ double z[256], z1[128], z2[64], z3[40], ze[40];
    __shared__ float  zm[3][128];
    __shared__ double zs[3][128];
    __shared__ double zmx, zl;
    // 768 reduction tasks: kind(0=max,1=sum) x level(3) x col(128).
    // 256 threads x 3 rounds; loads coalesced across the wave; 16-wide
    // batches give 16 outstanding loads per waitcnt.
    for (int rr=0; rr<3; rr++){
      int tau = t + rr*256;
      int kind = tau >> 8;              // 0: tau<384... (768/2=384) -> tau/384
      kind = tau / 384;
      int rem = tau - kind*384;
      int lvl = rem >> 7;
      int col = rem & 127;
      if (kind == 0){
        const float* ma = (lvl==0) ? rmax1 : ((lvl==1) ? rmax2 : rmax3);
        float m = -INFINITY;
        for (int q0=0;q0<PBLK;q0+=16){
          float v[16];
          #pragma unroll
          for (int u=0;u<16;u++) v[u] = ma[(size_t)(q0+u)*HH+col];
          #pragma unroll
          for (int u=0;u<16;u++) m = fmaxf(m, v[u]);
        }
        zm[lvl][col] = m;
      } else {
        const double* sa = (lvl==0) ? rsum1 : ((lvl==1) ? rsum2 : rsum3);
        double s = 0.0;
        for (int q0=0;q0<PBLK;q0+=16){
          double v[16];
          #pragma unroll
          for (int u=0;u<16;u++) v[u] = sa[(size_t)(q0+u)*HH+col];
          #pragma unroll
          for (int u=0;u<16;u++) s += v[u];     // q-ascending order preserved
        }
        zs[lvl][col] = s;
      }
    }
    __syncthreads();
    if (t < 128){
      z[t] = (double)zm[0][t] + (double)zm[1][t] + (double)zm[2][t];
    } else {
      int c = t-128;
      z[t] = zs[0][c]/4096.0 + zs[1][c]/2048.0 + zs[2][c]/1024.0;
    }
    __syncthreads();
    if (t<128){ double a=0; for(int k=0;k<256;k++) a += z[k]*(double)L1w[k*128+t]; z1[t]=a>0?a:0; }
    __syncthreads();
    if (t<64){ double a=0; for(int k=0;k<128;k++) a += z1[k]*(double)L2w[k*64+t]; z2[t]=a>0?a:0; }
    __syncthreads();
    if (t<40){ double a=0; for(int k=0;k<64;k++) a += z2[k]*(double)L3w[k*40+t]; z3[t]=a; }
    __syncthreads();
    if (t==0){
      double m=-INFINITY; for(int j=0;j<40;j++) m=fmax(m,z3[j]);
      zmx = m;
    }
    __syncthreads();
    if (t<40) ze[t] = exp(z3[t]-zmx);      // parallel exp, same values
    __syncthreads();
    if (t==0){
      double s=0; for(int j=0;j<40;j++) s+=ze[j];   // j-ascending, bit-identical
      zl = log(s);
    }
    __syncthreads();
    if (t<40) out_logp[t] = (float)(z3[t]-zmx-zl);
  }
}

__global__ void enc_kernel(float* out, float v){
  if (threadIdx.x < 40) out[threadIdx.x] = v;
}

extern "C" void kernel_launch(void* const* d_in, const int* in_sizes, int n_in,
                              void* d_out, int out_size, void* d_ws, size_t ws_size,
                              hipStream_t stream){
  const float* kp  = (const float*)d_in[0];
  const float* W1  = (const float*)d_in[2];
  const float* W2  = (const float*)d_in[4];
  const float* W3  = (const float*)d_in[6];
  const float* Wp1 = (const float*)d_in[8];
  const float* Wp2 = (const float*)d_in[10];
  const float* Wp3 = (const float*)d_in[12];
  const float* L1w = (const float*)d_in[14];
  const float* L2w = (const float*)d_in[16];
  const float* L3w = (const float*)d_in[18];

  float* out = (float*)d_out;
  if (out_size != 40 + 128*1024 + 1024 + 1024*1024){
    enc_kernel<<<1,64,0,stream>>>(out, (float)out_size);
    return;
  }

  char* p = (char*)d_ws;
  auto alloc = [&](size_t bytes)->char*{ char* q = p; p += (bytes + 255) & ~(size_t)255; return q; };
  float* G     = (float*)alloc((size_t)N0*HH*4);
  float* h     = (float*)alloc((size_t)N0*HH*4);
  float* hpA   = (float*)alloc((size_t)4096*HH*4);
  float* hpB   = (float*)alloc((size_t)2048*HH*4);
  int* degi    = (int*)alloc(N0*4);
  float* dinvf = (float*)alloc(N0*4);
  int* cnt     = (int*)alloc(N0*4);
  int* slots   = (int*)alloc((size_t)N0*32*4);
  int* nbr0    = (int*)alloc(N0*KN*4);
  int* nbr1    = (int*)alloc(4096*KN*4);
  int* nbr2    = (int*)alloc(2048*KN*4);
  int* nbr3    = (int*)alloc(1024*KN*4);
  int* idx1    = (int*)alloc(4096*4);
  int* idx2    = (int*)alloc(2048*4);
  int* idx3    = (int*)alloc(1024*4);
  int* perm1   = (int*)alloc(4096*4);
  int* perm2   = (int*)alloc(2048*4);
  int* perm3   = (int*)alloc(1024*4);
  int* pos     = (int*)alloc(N0*4);
  float* ybuf  = (float*)alloc(N0*4);
  float* score = (float*)alloc(N0*4);
  unsigned* skey = (unsigned*)alloc(N0*4);
  float* gate  = (float*)alloc(4096*4);
  double* TsBlk = (double*)alloc((size_t)NBLK*HH*8);
  double* TsPart = (double*)alloc(256*8);
  float* rmax1 = (float*)alloc((size_t)PBLK*HH*4);
  float* rmax2 = (float*)alloc((size_t)PBLK*HH*4);
  float* rmax3 = (float*)alloc((size_t)PBLK*HH*4);
  double* rsum1 = (double*)alloc((size_t)PBLK*HH*8);
  double* rsum2 = (double*)alloc((size_t)PBLK*HH*8);
  double* rsum3 = (double*)alloc((size_t)PBLK*HH*8);

  float* out_logp = out;
  float* out_xs   = out + 40;
  float* out_perm = out + 40 + 128*1024;
  float* out_a3   = out_perm + 1024;

  auto run_level = [&](int n, int init, const float* X, const float* W, const float* Wp,
                       int* nbr, int* nbrN, int* idx, int* permPrev, int* permNext,
                       float* hp, float* rmaxB, double* rsumB){
    int m = n>>1;
    graph_kernel<<<1,1024,(size_t)n*8,stream>>>(nbr, n, init, degi, dinvf, cnt, slots, TsPart);
    gemmT_kernel<<<NBLK,HH,0,stream>>>(X, W, dinvf, G, TsBlk, n/NBLK);
    aggproj_kernel<<<n,HH,0,stream>>>(G, dinvf, degi, cnt, slots, TsBlk, Wp, h, ybuf, TsPart, n);
    sagg32_kernel<<<(n+255)/256,256,0,stream>>>(ybuf, dinvf, degi, cnt, slots, TsPart, score, skey, n);
    rank_kernel<<<n/EL,256,0,stream>>>(skey, score, n, idx, gate, pos, permPrev, permNext);
    poolmap_kernel<<<PBLK,HH,0,stream>>>(h, idx, gate, nbr, pos, hp, nbrN, rmaxB, rsumB, m/PBLK);
  };

  run_level(8192, 1, kp,  W1, Wp1, nbr0, nbr1, idx1, nullptr, perm1, hpA, rmax1, rsum1);
  run_level(4096, 0, hpA, W2, Wp2, nbr1, nbr2, idx2, perm1,   perm2, hpB, rmax2, rsum2);
  run_level(2048, 0, hpB, W3, Wp3, nbr2, nbr3, idx3, perm2,   perm3, hpA, rmax3, rsum3);

  epilogue_kernel<<<2050,256,0,stream>>>(kp, perm3, nbr3,
                                         rmax1, rmax2, rmax3, rsum1, rsum2, rsum3,
                                         L1w, L2w, L3w,
                                         out_logp, out_xs, out_perm, out_a3);
}